// Round 1
// baseline (13050.925 us; speedup 1.0000x reference)
//
#include <hip/hip_runtime.h>
#include <stdint.h>

// ---------------- model constants ----------------
#define S_LEN 4096
#define NB 2
#define DMODEL 768
#define NHEAD 12
#define DHEAD 64
#define WWIN 256
#define NCHUNK 16      // S_LEN / WWIN
#define FDIM 3072
#define NLAYER 12
#define NTOK 8192      // NB * S_LEN

typedef unsigned short u16;
typedef __attribute__((ext_vector_type(8))) short bf16x8;
typedef __attribute__((ext_vector_type(4))) float f32x4;

__device__ __forceinline__ float blo(uint32_t w){ return __builtin_bit_cast(float, (uint32_t)(w<<16)); }
__device__ __forceinline__ float bhi(uint32_t w){ return __builtin_bit_cast(float, (uint32_t)(w & 0xffff0000u)); }
__device__ __forceinline__ float bf2f(u16 u){ return __builtin_bit_cast(float, (uint32_t)(((uint32_t)u)<<16)); }
__device__ __forceinline__ u16 f2bf(float f){
  uint32_t x = __builtin_bit_cast(uint32_t, f);
  x += 0x7fffu + ((x>>16)&1u);     // RNE
  return (u16)(x>>16);
}
__device__ __forceinline__ uint32_t pk(float a, float b){
  return (uint32_t)f2bf(a) | ((uint32_t)f2bf(b)<<16);
}
// flag-aware load of an input float array (isF32: 1 = fp32, 0 = bf16)
__device__ __forceinline__ float ldf(const void* p, long i, int isF32){
  return isF32 ? ((const float*)p)[i] : bf2f(((const u16*)p)[i]);
}

// ---------------- dtype probe: emb_ln_w is ones ----------------
// fp32 1.0 little-endian: u16[0]=0x0000 ; bf16 1.0: u16[0]=0x3F80
__global__ void probe_dtype(const u16* __restrict__ lnw, int* __restrict__ flag){
  if (threadIdx.x==0 && blockIdx.x==0) *flag = (lnw[0]==0x3F80) ? 0 : 1;
}

// ---------------- block reduce (sum, sumsq) ----------------
__device__ __forceinline__ void block_reduce2(float& s, float& ss, int t){
  #pragma unroll
  for (int off=32; off>=1; off>>=1){
    s  += __shfl_down(s,  off, 64);
    ss += __shfl_down(ss, off, 64);
  }
  __shared__ float rs[4], rss[4];
  if ((t&63)==0){ rs[t>>6]=s; rss[t>>6]=ss; }
  __syncthreads();
  s  = rs[0]+rs[1]+rs[2]+rs[3];
  ss = rss[0]+rss[1]+rss[2]+rss[3];
}

// ---------------- weight transpose with element offset (any float dtype -> bf16) ----------------
__global__ __launch_bounds__(256) void transpose_off(
    const void* __restrict__ in, long eoff, u16* __restrict__ out,
    int R, int C, const int* __restrict__ flag)
{
  const int isF32 = *flag;
  __shared__ u16 tile[32][33];
  int x = blockIdx.x*32 + threadIdx.x;
  int ybase = blockIdx.y*32;
  #pragma unroll
  for (int j=threadIdx.y; j<32; j+=8){
    long idx = eoff + (long)(ybase+j)*C + x;
    tile[j][threadIdx.x] = isF32 ? f2bf(((const float*)in)[idx])
                                 : ((const u16*)in)[idx];
  }
  __syncthreads();
  int ox = ybase + threadIdx.x;       // out col (= in row)
  int oybase = blockIdx.x*32;         // out row (= in col)
  #pragma unroll
  for (int j=threadIdx.y; j<32; j+=8)
    out[(size_t)(oybase+j)*R + ox] = tile[threadIdx.x][j];
}

// ---------------- embedding gather + LayerNorm ----------------
__global__ __launch_bounds__(256) void embed_ln(
    const int* __restrict__ ids, const void* __restrict__ wemb,
    const void* __restrict__ pemb, const void* __restrict__ temb,
    const void* __restrict__ gw, const void* __restrict__ gb,
    float* __restrict__ hf, const int* __restrict__ flag)
{
  const int isF32 = *flag;
  int r = blockIdx.x, t = threadIdx.x;
  int spos = r & (S_LEN-1);
  int tok = ids[r];
  size_t base = (size_t)r*DMODEL;
  float x[3]; float s=0.f, ss=0.f;
  #pragma unroll
  for (int i=0;i<3;i++){
    int idx = t + 256*i;
    float v = ldf(wemb, (long)tok*DMODEL+idx, isF32)
            + ldf(pemb, (long)(spos+2)*DMODEL+idx, isF32)
            + ldf(temb, idx, isF32);
    x[i]=v; s+=v; ss+=v*v;
  }
  block_reduce2(s, ss, t);
  float mu = s*(1.f/768.f);
  float var = ss*(1.f/768.f) - mu*mu;
  float rstd = rsqrtf(var + 1e-5f);
  #pragma unroll
  for (int i=0;i<3;i++){
    int idx = t + 256*i;
    float y = (x[i]-mu)*rstd*ldf(gw,idx,isF32) + ldf(gb,idx,isF32);
    hf[base+idx] = y;
  }
}

// ---------------- residual add + LayerNorm (in-place on hf); delta is bf16 ----------------
// gw/gb are indexed with element offset goff (per-layer slice).
__global__ __launch_bounds__(256) void add_ln(
    float* __restrict__ hf, const u16* __restrict__ delta,
    const void* __restrict__ gw, const void* __restrict__ gb, long goff,
    const int* __restrict__ flag)
{
  const int isF32 = *flag;
  int r = blockIdx.x, t = threadIdx.x;
  size_t base = (size_t)r*DMODEL;
  float x[3]; float s=0.f, ss=0.f;
  #pragma unroll
  for (int i=0;i<3;i++){
    int idx = t + 256*i;
    float v = hf[base+idx] + bf2f(delta[base+idx]);
    x[i]=v; s+=v; ss+=v*v;
  }
  block_reduce2(s, ss, t);
  float mu = s*(1.f/768.f);
  float var = ss*(1.f/768.f) - mu*mu;
  float rstd = rsqrtf(var + 1e-5f);
  #pragma unroll
  for (int i=0;i<3;i++){
    int idx = t + 256*i;
    float y = (x[i]-mu)*rstd*ldf(gw,goff+idx,isF32) + ldf(gb,goff+idx,isF32);
    hf[base+idx] = y;
  }
}

// ---------------- bf16 MFMA GEMM: C[M,N] = A[M,K] * Bt[N,K]^T + bias -> bf16 ----------------
// 64x64 tile, BK=64, 4 waves each computing 32x32.
// AF32: A is fp32 (converted to bf16 during LDS staging); else A is bf16.
// bias segmented over arrays b0/b1/b2 of width bw (packed QKV); boff = per-layer elem offset.
template<bool GELU, bool AF32>
__global__ __launch_bounds__(256) void gemm_bt(
    const void* __restrict__ A, const u16* __restrict__ Bt,
    const void* __restrict__ b0, const void* __restrict__ b1,
    const void* __restrict__ b2, int bw, long boff,
    u16* __restrict__ Cb, int M, int N, int K, const int* __restrict__ flag)
{
  const int isF32 = *flag;
  constexpr int LDT = 72;  // padded LDS row stride; 144B (9x16B) keeps 16B alignment; 2-way bank alias (free)
  __shared__ __attribute__((aligned(16))) u16 As[64*LDT];
  __shared__ __attribute__((aligned(16))) u16 Bs[64*LDT];
  const int t = threadIdx.x;
  const int mBase = blockIdx.y*64, nBase = blockIdx.x*64;
  const int lane = t & 63, wave = t >> 6;
  const int wm = (wave>>1)*32, wn = (wave&1)*32;
  const int lrow = lane & 15, quad = lane >> 4;
  f32x4 acc[2][2] = {};
  const int lr = t >> 2;
  const int lc = (t & 3) * 16;
  const u16* Bg = Bt + (size_t)(nBase+lr)*K + lc;
  u16* AsW = &As[lr*LDT + lc];
  u16* BsW = &Bs[lr*LDT + lc];
  const u16*   Agh = (const u16*)A  + (size_t)(mBase+lr)*K + lc;
  const float* Agf = (const float*)A + (size_t)(mBase+lr)*K + lc;
  for (int k0 = 0; k0 < K; k0 += 64){
    uint4 a0, a1;
    if (AF32){
      float4 f0 = *(const float4*)(Agf + k0);
      float4 f1 = *(const float4*)(Agf + k0 + 4);
      float4 f2 = *(const float4*)(Agf + k0 + 8);
      float4 f3 = *(const float4*)(Agf + k0 + 12);
      a0.x = pk(f0.x,f0.y); a0.y = pk(f0.z,f0.w);
      a0.z = pk(f1.x,f1.y); a0.w = pk(f1.z,f1.w);
      a1.x = pk(f2.x,f2.y); a1.y = pk(f2.z,f2.w);
      a1.z = pk(f3.x,f3.y); a1.w = pk(f3.z,f3.w);
    } else {
      a0 = *(const uint4*)(Agh + k0);
      a1 = *(const uint4*)(Agh + k0 + 8);
    }
    uint4 b0v = *(const uint4*)(Bg + k0);
    uint4 b1v = *(const uint4*)(Bg + k0 + 8);
    __syncthreads();               // previous iteration's LDS reads done
    *(uint4*)(AsW)   = a0;  *(uint4*)(AsW+8) = a1;
    *(uint4*)(BsW)   = b0v; *(uint4*)(BsW+8) = b1v;
    __syncthreads();
    #pragma unroll
    for (int kk=0; kk<64; kk+=32){
      bf16x8 af0 = *(const bf16x8*)&As[(wm     +lrow)*LDT + kk + quad*8];
      bf16x8 af1 = *(const bf16x8*)&As[(wm+16  +lrow)*LDT + kk + quad*8];
      bf16x8 bt0 = *(const bf16x8*)&Bs[(wn     +lrow)*LDT + kk + quad*8];
      bf16x8 bt1 = *(const bf16x8*)&Bs[(wn+16  +lrow)*LDT + kk + quad*8];
      acc[0][0] = __builtin_amdgcn_mfma_f32_16x16x32_bf16(af0,bt0,acc[0][0],0,0,0);
      acc[0][1] = __builtin_amdgcn_mfma_f32_16x16x32_bf16(af0,bt1,acc[0][1],0,0,0);
      acc[1][0] = __builtin_amdgcn_mfma_f32_16x16x32_bf16(af1,bt0,acc[1][0],0,0,0);
      acc[1][1] = __builtin_amdgcn_mfma_f32_16x16x32_bf16(af1,bt1,acc[1][1],0,0,0);
    }
  }
  #pragma unroll
  for (int mi=0;mi<2;mi++){
    #pragma unroll
    for (int ni=0;ni<2;ni++){
      int col = nBase + wn + ni*16 + lrow;
      const void* bp; long bidx;
      if      (col <   bw){ bp=b0; bidx=boff+col; }
      else if (col < 2*bw){ bp=b1; bidx=boff+col-bw; }
      else                { bp=b2; bidx=boff+col-2*bw; }
      float bval = ldf(bp, bidx, isF32);
      #pragma unroll
      for (int r=0;r<4;r++){
        int row = mBase + wm + mi*16 + quad*4 + r;
        float v = acc[mi][ni][r] + bval;
        if (GELU) v = 0.5f*v*(1.0f + erff(v*0.70710678118654752f));
        Cb[(size_t)row*N + col] = f2bf(v);
      }
    }
  }
}

// ---------------- sliding-window attention ----------------
// grid (C=16, H=12, B=2), block 256: thread p owns query p of chunk c.
// Online softmax over 5 sub-tiles of 128 keys covering [pg-256, pg+256].
//
// LDS layout: XOR-swizzled. In the compute loop, j is per-lane (j = p + const),
// so 64 lanes of a wave read 64 CONSECUTIVE rows at the same dg. With a linear
// [128][64] u16 layout that's a 128-B stride -> all lanes in one 4-bank group
// (16-way conflict, ~5.7x serialization, m136). Swizzling the 16-B slot index
// by (j&7) spreads consecutive rows across all 32 banks on both the staging
// write (8 lanes/row still write 8 distinct slots) and the compute read.
__device__ __forceinline__ int swz(int j, int dg){
  return j*64 + (dg ^ ((j & 7) << 3));   // dg is a multiple of 8 (16-B slots)
}

__global__ __launch_bounds__(256) void attn_sliding(
    const u16* __restrict__ qkv,     // [NTOK][2304]: q|k|v
    const int* __restrict__ mask,    // [NB][S_LEN]
    u16* __restrict__ attnO)         // [NTOK][768]
{
  __shared__ __attribute__((aligned(16))) u16 Ks[128*64];
  __shared__ __attribute__((aligned(16))) u16 Vs[128*64];
  __shared__ unsigned char Mk[128];
  const int c = blockIdx.x, hh = blockIdx.y, b = blockIdx.z;
  const int p = threadIdx.x;
  const int pg = c*WWIN + p;                 // global query position
  const size_t qrow = (size_t)b*S_LEN + pg;
  const u16* qp = qkv + qrow*2304 + hh*DHEAD;
  float q[64];
  #pragma unroll
  for (int dg=0; dg<64; dg+=8){
    uint4 u = *(const uint4*)(qp+dg);
    q[dg+0]=blo(u.x); q[dg+1]=bhi(u.x);
    q[dg+2]=blo(u.y); q[dg+3]=bhi(u.y);
    q[dg+4]=blo(u.z); q[dg+5]=bhi(u.z);
    q[dg+6]=blo(u.w); q[dg+7]=bhi(u.w);
  }
  float O[64];
  #pragma unroll
  for (int d=0;d<64;d++) O[d]=0.f;
  float m=-1e30f, l=0.f;

  for (int st=0; st<5; st++){                // 5 sub-tiles x 128 keys cover [pg-256, pg+256]
    const int base = (c-1)*WWIN + st*128;
    __syncthreads();   // previous sub-tile's LDS reads complete
    #pragma unroll
    for (int it=0; it<4; it++){
      int idx = it*256 + p;                  // 0..1023
      int j = idx>>3, dg = (idx&7)*8;
      int g = base + j;
      uint4 kv = {0,0,0,0}, vv = {0,0,0,0};
      if (g>=0 && g<S_LEN){
        const u16* kb = qkv + ((size_t)b*S_LEN+g)*2304 + 768 + hh*DHEAD + dg;
        kv = *(const uint4*)kb;
        vv = *(const uint4*)(kb + 768);
      }
      *(uint4*)&Ks[swz(j,dg)] = kv;
      *(uint4*)&Vs[swz(j,dg)] = vv;
    }
    if (p < 128){
      int g = base + p;
      Mk[p] = (g>=0 && g<S_LEN) ? (unsigned char)(mask[b*S_LEN+g]!=0) : (unsigned char)0;
    }
    __syncthreads();

    int lo = pg - WWIN - base; if (lo < 0) lo = 0;
    int hi = pg + WWIN - base; if (hi > 127) hi = 127;
    for (int j=lo; j<=hi; j++){
      if (!Mk[j]) continue;
      int jx = (j & 7) << 3;
      float s=0.f;
      #pragma unroll
      for (int dg=0;dg<64;dg+=8){
        uint4 u = *(const uint4*)&Ks[j*64 + (dg ^ jx)];
        s += blo(u.x)*q[dg+0]+bhi(u.x)*q[dg+1]+blo(u.y)*q[dg+2]+bhi(u.y)*q[dg+3]
           + blo(u.z)*q[dg+4]+bhi(u.z)*q[dg+5]+blo(u.w)*q[dg+6]+bhi(u.w)*q[dg+7];
      }
      s *= 0.125f;                       // 1/sqrt(64)
      if (s > m){
        float corr = __expf(m - s);
        m = s; l *= corr;
        #pragma unroll
        for (int d=0;d<64;d++) O[d]*=corr;
      }
      float w = __expf(s - m);
      l += w;
      #pragma unroll
      for (int dg=0;dg<64;dg+=8){
        uint4 u = *(const uint4*)&Vs[j*64 + (dg ^ jx)];
        O[dg+0]+=w*blo(u.x); O[dg+1]+=w*bhi(u.x);
        O[dg+2]+=w*blo(u.y); O[dg+3]+=w*bhi(u.y);
        O[dg+4]+=w*blo(u.z); O[dg+5]+=w*bhi(u.z);
        O[dg+6]+=w*blo(u.w); O[dg+7]+=w*bhi(u.w);
      }
    }
  }
  float inv = 1.0f/l;
  u16* op = attnO + qrow*DMODEL + hh*DHEAD;
  #pragma unroll
  for (int dg=0;dg<64;dg+=8){
    uint4 u;
    u.x = pk(O[dg+0]*inv, O[dg+1]*inv);
    u.y = pk(O[dg+2]*inv, O[dg+3]*inv);
    u.z = pk(O[dg+4]*inv, O[dg+5]*inv);
    u.w = pk(O[dg+6]*inv, O[dg+7]*inv);
    *(uint4*)(op+dg) = u;
  }
}

// ---------------- regression head ----------------
__global__ __launch_bounds__(256) void head_kernel(
    const float* __restrict__ hf, const void* __restrict__ Wr1,
    const void* __restrict__ br1, const void* __restrict__ Wr2,
    const void* __restrict__ br2, void* __restrict__ outp,
    const int* __restrict__ flag)
{
  const int isF32 = *flag;
  int b = blockIdx.x, t = threadIdx.x;
  __shared__ float xs[DMODEL];
  const float* x = hf + (size_t)b*S_LEN*DMODEL;   // pooled = row 0 of batch b
  for (int i=t;i<DMODEL;i+=256) xs[i]=x[i];
  __syncthreads();
  float acc=0.f;
  #pragma unroll
  for (int jj=0;jj<2;jj++){
    int jcol = t + jj*256;
    float hsum = ldf(br1, jcol, isF32);
    for (int d=0;d<DMODEL;d++) hsum += xs[d]*ldf(Wr1, (long)d*512 + jcol, isF32);
    hsum = fmaxf(hsum, 0.f);
    acc += hsum * ldf(Wr2, jcol, isF32);
  }
  #pragma unroll
  for (int off=32; off>=1; off>>=1) acc += __shfl_down(acc, off, 64);
  __shared__ float rs[4];
  if ((t&63)==0) rs[t>>6]=acc;
  __syncthreads();
  if (t==0){
    float val = rs[0]+rs[1]+rs[2]+rs[3] + ldf(br2, 0, isF32);
    if (isF32) ((float*)outp)[b] = val;
    else       ((u16*)outp)[b]   = f2bf(val);
  }
}

// ---------------- workspace layout (bytes), total 102,236,416 (~97.5 MiB) ----------------
static const size_t OFF_WT   = 0;          // 14,155,776: qkvT|woT|wiT|wfT (one layer, reused)
static const size_t OFF_FLAG = 14155776;   // 256
static const size_t OFF_HF   = 14156032;   // 25,165,824 fp32 residual
static const size_t OFF_X    = 39321856;   // 37,748,736 qkv [8192][2304] bf16 / ffn1 chunk [2048][3072] bf16
static const size_t OFF_ATT  = 77070592;   // 12,582,912 attO bf16
static const size_t OFF_DLT  = 89653504;   // 12,582,912 delta bf16

extern "C" void kernel_launch(void* const* d_in, const int* in_sizes, int n_in,
                              void* d_out, int out_size, void* d_ws, size_t ws_size,
                              hipStream_t stream)
{
  const int*  ids   = (const int*)d_in[0];
  const int*  amask = (const int*)d_in[1];
  const void* wemb  = d_in[2];
  const void* pemb  = d_in[3];
  const void* temb  = d_in[4];
  const void* elnw  = d_in[5];
  const void* elnb  = d_in[6];
  const void* Wq    = d_in[7];
  const void* bq    = d_in[8];
  const void* Wk    = d_in[9];
  const void* bk    = d_in[10];
  const void* Wv    = d_in[11];
  const void* bv    = d_in[12];
  const void* Wo    = d_in[13];
  const void* bo    = d_in[14];
  const void* ln1w  = d_in[15];
  const void* ln1b  = d_in[16];
  const void* Wi    = d_in[17];
  const void* bi    = d_in[18];
  const void* Wf    = d_in[19];
  const void* bfb   = d_in[20];
  const void* ln2w  = d_in[21];
  const void* ln2b  = d_in[22];
  const void* Wr1   = d_in[23];
  const void* br1   = d_in[24];
  const void* Wr2   = d_in[25];
  const void* br2   = d_in[26];

  char* ws = (char*)d_ws;
  u16*   qkvT   = (u16*)  (ws + OFF_WT);                 // [2304][768]
  u16*   woT    = qkvT + (size_t)2304*768;               // [768][768]
  u16*   wiT    = woT  + (size_t)768*768;                // [3072][768]
  u16*   wfT    = wiT  + (size_t)3072*768;               // [768][3072]
  int*   flag   = (int*)  (ws + OFF_FLAG);
  float* hf     = (float*)(ws + OFF_HF);
  u16*   qkvbuf = (u16*)  (ws + OFF_X);
  u16*   ffn1   = (u16*)  (ws + OFF_X);
  u16*   attO   = (u16*)  (ws + OFF_ATT);
  u16*   delta  = (u16*)  (ws + OFF_DLT);

  const long wDD = (long)768*768, wDF = (long)768*3072;
  dim3 tb(32,8);

  probe_dtype<<<1, 1, 0, stream>>>((const u16*)elnw, flag);
  embed_ln<<<NTOK, 256, 0, stream>>>(ids, wemb, pemb, temb, elnw, elnb, hf, flag);

  for (int l=0; l<NLAYER; l++){
    transpose_off<<<dim3(24,24), tb, 0, stream>>>(Wq, (long)l*wDD, qkvT,            768, 768,  flag);
    transpose_off<<<dim3(24,24), tb, 0, stream>>>(Wk, (long)l*wDD, qkvT + 768*768,  768, 768,  flag);
    transpose_off<<<dim3(24,24), tb, 0, stream>>>(Wv, (long)l*wDD, qkvT + 1536*768, 768, 768,  flag);
    transpose_off<<<dim3(24,24), tb, 0, stream>>>(Wo, (long)l*wDD, woT,             768, 768,  flag);
    transpose_off<<<dim3(96,24), tb, 0, stream>>>(Wi, (long)l*wDF, wiT,             768, 3072, flag);
    transpose_off<<<dim3(24,96), tb, 0, stream>>>(Wf, (long)l*wDF, wfT,             3072, 768, flag);

    // QKV projection (packed N=2304), A = fp32 residual -> bf16 qkv
    gemm_bt<false,true><<<dim3(36,128), 256, 0, stream>>>(
        hf, qkvT, bq, bk, bv, 768, (long)l*768, qkvbuf, NTOK, 2304, 768, flag);
    // sliding-window attention -> bf16 [NTOK,768]
    attn_sliding<<<dim3(NCHUNK,NHEAD,NB), 256, 0, stream>>>(qkvbuf, amask, attO);
    // output projection -> bf16 delta
    gemm_bt<false,false><<<dim3(12,128), 256, 0, stream>>>(
        attO, woT, bo, bo, bo, 768, (long)l*768, delta, NTOK, 768, 768, flag);
    add_ln<<<NTOK, 256, 0, stream>>>(hf, delta, ln1w, ln1b, (long)l*768, flag);

    // FFN chunked over M (ffn1 aliases the dead qkv region)
    for (int mc=0; mc<4; mc++){
      gemm_bt<true,true><<<dim3(48,32), 256, 0, stream>>>(
          hf + (size_t)mc*2048*768, wiT, bi, bi, bi, 3072, (long)l*3072,
          ffn1, 2048, 3072, 768, flag);
      gemm_bt<false,false><<<dim3(12,32), 256, 0, stream>>>(
          ffn1, wfT, bfb, bfb, bfb, 768, (long)l*768,
          delta + (size_t)mc*2048*768, 2048, 768, 3072, flag);
    }
    add_ln<<<NTOK, 256, 0, stream>>>(hf, delta, ln2w, ln2b, (long)l*768, flag);
  }

  head_kernel<<<NB, 256, 0, stream>>>(hf, Wr1, br1, Wr2, br2, d_out, flag);
}

// Round 3
// 11247.231 us; speedup vs baseline: 1.1604x; 1.1604x over previous
//
#include <hip/hip_runtime.h>
#include <stdint.h>

// ---------------- model constants ----------------
#define S_LEN 4096
#define NB 2
#define DMODEL 768
#define NHEAD 12
#define DHEAD 64
#define WWIN 256
#define NCHUNK 16      // S_LEN / WWIN
#define FDIM 3072
#define NLAYER 12
#define NTOK 8192      // NB * S_LEN

typedef unsigned short u16;
typedef __attribute__((ext_vector_type(8))) short bf16x8;
typedef __attribute__((ext_vector_type(4))) float f32x4;

__device__ __forceinline__ float blo(uint32_t w){ return __builtin_bit_cast(float, (uint32_t)(w<<16)); }
__device__ __forceinline__ float bhi(uint32_t w){ return __builtin_bit_cast(float, (uint32_t)(w & 0xffff0000u)); }
__device__ __forceinline__ float bf2f(u16 u){ return __builtin_bit_cast(float, (uint32_t)(((uint32_t)u)<<16)); }
__device__ __forceinline__ u16 f2bf(float f){
  uint32_t x = __builtin_bit_cast(uint32_t, f);
  x += 0x7fffu + ((x>>16)&1u);     // RNE
  return (u16)(x>>16);
}
__device__ __forceinline__ uint32_t pk(float a, float b){
  return (uint32_t)f2bf(a) | ((uint32_t)f2bf(b)<<16);
}
// flag-aware load of an input float array (isF32: 1 = fp32, 0 = bf16)
__device__ __forceinline__ float ldf(const void* p, long i, int isF32){
  return isF32 ? ((const float*)p)[i] : bf2f(((const u16*)p)[i]);
}
// async global->LDS, 16B per lane; lds must be wave-uniform (HW: base + lane*16)
__device__ __forceinline__ void async_ld16(u16* lds, const u16* g){
  __builtin_amdgcn_global_load_lds(
      (const __attribute__((address_space(1))) unsigned int*)g,
      (__attribute__((address_space(3))) unsigned int*)lds,
      16, 0, 0);
}

// ---------------- dtype probe: emb_ln_w is ones ----------------
// fp32 1.0 little-endian: u16[0]=0x0000 ; bf16 1.0: u16[0]=0x3F80
__global__ void probe_dtype(const u16* __restrict__ lnw, int* __restrict__ flag){
  if (threadIdx.x==0 && blockIdx.x==0) *flag = (lnw[0]==0x3F80) ? 0 : 1;
}

// ---------------- block reduce (sum, sumsq) ----------------
__device__ __forceinline__ void block_reduce2(float& s, float& ss, int t){
  #pragma unroll
  for (int off=32; off>=1; off>>=1){
    s  += __shfl_down(s,  off, 64);
    ss += __shfl_down(ss, off, 64);
  }
  __shared__ float rs[4], rss[4];
  if ((t&63)==0){ rs[t>>6]=s; rss[t>>6]=ss; }
  __syncthreads();
  s  = rs[0]+rs[1]+rs[2]+rs[3];
  ss = rss[0]+rss[1]+rss[2]+rss[3];
}

// ---------------- weight transpose with element offset (any float dtype -> bf16) ----------------
__global__ __launch_bounds__(256) void transpose_off(
    const void* __restrict__ in, long eoff, u16* __restrict__ out,
    int R, int C, const int* __restrict__ flag)
{
  const int isF32 = *flag;
  __shared__ u16 tile[32][33];
  int x = blockIdx.x*32 + threadIdx.x;
  int ybase = blockIdx.y*32;
  #pragma unroll
  for (int j=threadIdx.y; j<32; j+=8){
    long idx = eoff + (long)(ybase+j)*C + x;
    tile[j][threadIdx.x] = isF32 ? f2bf(((const float*)in)[idx])
                                 : ((const u16*)in)[idx];
  }
  __syncthreads();
  int ox = ybase + threadIdx.x;       // out col (= in row)
  int oybase = blockIdx.x*32;         // out row (= in col)
  #pragma unroll
  for (int j=threadIdx.y; j<32; j+=8)
    out[(size_t)(oybase+j)*R + ox] = tile[threadIdx.x][j];
}

// ---------------- embedding gather + LayerNorm (writes fp32 hf AND bf16 hb) ----------------
__global__ __launch_bounds__(256) void embed_ln(
    const int* __restrict__ ids, const void* __restrict__ wemb,
    const void* __restrict__ pemb, const void* __restrict__ temb,
    const void* __restrict__ gw, const void* __restrict__ gb,
    float* __restrict__ hf, u16* hb, const int* __restrict__ flag)
{
  const int isF32 = *flag;
  int r = blockIdx.x, t = threadIdx.x;
  int spos = r & (S_LEN-1);
  int tok = ids[r];
  size_t base = (size_t)r*DMODEL;
  float x[3]; float s=0.f, ss=0.f;
  #pragma unroll
  for (int i=0;i<3;i++){
    int idx = t + 256*i;
    float v = ldf(wemb, (long)tok*DMODEL+idx, isF32)
            + ldf(pemb, (long)(spos+2)*DMODEL+idx, isF32)
            + ldf(temb, idx, isF32);
    x[i]=v; s+=v; ss+=v*v;
  }
  block_reduce2(s, ss, t);
  float mu = s*(1.f/768.f);
  float var = ss*(1.f/768.f) - mu*mu;
  float rstd = rsqrtf(var + 1e-5f);
  #pragma unroll
  for (int i=0;i<3;i++){
    int idx = t + 256*i;
    float y = (x[i]-mu)*rstd*ldf(gw,idx,isF32) + ldf(gb,idx,isF32);
    hf[base+idx] = y;
    hb[base+idx] = f2bf(y);
  }
}

// ---------------- residual add + LayerNorm (in-place on hf); delta is bf16 ----------------
// Also emits the normalized output as bf16 into hb (which MAY alias delta:
// each thread reads its delta elements before writing them, separated by the
// reduce barrier, and no cross-thread element sharing).
__global__ __launch_bounds__(256) void add_ln(
    float* __restrict__ hf, const u16* delta,
    const void* __restrict__ gw, const void* __restrict__ gb, long goff,
    u16* hb, const int* __restrict__ flag)
{
  const int isF32 = *flag;
  int r = blockIdx.x, t = threadIdx.x;
  size_t base = (size_t)r*DMODEL;
  float x[3]; float s=0.f, ss=0.f;
  #pragma unroll
  for (int i=0;i<3;i++){
    int idx = t + 256*i;
    float v = hf[base+idx] + bf2f(delta[base+idx]);
    x[i]=v; s+=v; ss+=v*v;
  }
  block_reduce2(s, ss, t);
  float mu = s*(1.f/768.f);
  float var = ss*(1.f/768.f) - mu*mu;
  float rstd = rsqrtf(var + 1e-5f);
  #pragma unroll
  for (int i=0;i<3;i++){
    int idx = t + 256*i;
    float y = (x[i]-mu)*rstd*ldf(gw,goff+idx,isF32) + ldf(gb,goff+idx,isF32);
    hf[base+idx] = y;
    hb[base+idx] = f2bf(y);
  }
}

// ---------------- bf16 MFMA GEMM, m97 structure ----------------
// C[M,N] = A[M,K] * Bt[N,K]^T + bias -> bf16.  A and Bt are bf16.
// 128x128 tile, BK=64, 4 waves each computing 64x64 (4x4 of 16x16x32 MFMA).
// Staging: global_load_lds width 16, linear LDS [128][64] (wave-uniform dest).
// bias segmented over arrays b0/b1/b2 of width bw (packed QKV); boff = per-layer elem offset.
template<bool GELU>
__global__ __launch_bounds__(256) void gemm128(
    const u16* __restrict__ A, const u16* __restrict__ Bt,
    const void* __restrict__ b0, const void* __restrict__ b1,
    const void* __restrict__ b2, int bw, long boff,
    u16* __restrict__ Cb, int M, int N, int K, const int* __restrict__ flag)
{
  const int isF32 = *flag;
  __shared__ __attribute__((aligned(16))) u16 As[128*64];
  __shared__ __attribute__((aligned(16))) u16 Bs[128*64];
  const int t = threadIdx.x;
  const int lane = t & 63, wave = t >> 6;
  const int mBase = blockIdx.y*128, nBase = blockIdx.x*128;
  const int wm = (wave>>1)*64, wn = (wave&1)*64;   // wave's 64x64 output corner
  const int lrow = lane & 15, quad = lane >> 4;
  f32x4 acc[4][4] = {};

  // staging geometry: per issue i (0..3), wave covers rows i*32 + wave*8 .. +8
  const int sr = wave*8 + (lane>>3);     // lane's row within the 32-row group
  const int sc = (lane&7)*8;             // lane's 8-elem (16B) column chunk
  const u16* Ag = A  + (size_t)(mBase + sr)*K + sc;
  const u16* Bg = Bt + (size_t)(nBase + sr)*K + sc;
  u16* AsW = &As[(wave*8)*64];           // wave-uniform LDS base
  u16* BsW = &Bs[(wave*8)*64];

  for (int k0 = 0; k0 < K; k0 += 64){
    __syncthreads();                     // previous iteration's LDS reads done
    #pragma unroll
    for (int i=0;i<4;i++){
      async_ld16(AsW + i*32*64, Ag + (size_t)i*32*K + k0);
      async_ld16(BsW + i*32*64, Bg + (size_t)i*32*K + k0);
    }
    __syncthreads();                     // compiler drains vmcnt(0) before barrier
    #pragma unroll
    for (int kk=0; kk<64; kk+=32){
      bf16x8 af[4], bg[4];
      #pragma unroll
      for (int mi=0;mi<4;mi++) af[mi] = *(const bf16x8*)&As[(wm+mi*16+lrow)*64 + kk + quad*8];
      #pragma unroll
      for (int ni=0;ni<4;ni++) bg[ni] = *(const bf16x8*)&Bs[(wn+ni*16+lrow)*64 + kk + quad*8];
      #pragma unroll
      for (int mi=0;mi<4;mi++){
        #pragma unroll
        for (int ni=0;ni<4;ni++){
          acc[mi][ni] = __builtin_amdgcn_mfma_f32_16x16x32_bf16(af[mi], bg[ni], acc[mi][ni], 0,0,0);
        }
      }
    }
  }

  #pragma unroll
  for (int mi=0;mi<4;mi++){
    #pragma unroll
    for (int ni=0;ni<4;ni++){
      int col = nBase + wn + ni*16 + lrow;
      const void* bp; long bidx;
      if      (col <   bw){ bp=b0; bidx=boff+col; }
      else if (col < 2*bw){ bp=b1; bidx=boff+col-bw; }
      else                { bp=b2; bidx=boff+col-2*bw; }
      float bval = ldf(bp, bidx, isF32);
      #pragma unroll
      for (int r=0;r<4;r++){
        int row = mBase + wm + mi*16 + quad*4 + r;
        float v = acc[mi][ni][r] + bval;
        if (GELU) v = 0.5f*v*(1.0f + erff(v*0.70710678118654752f));
        Cb[(size_t)row*N + col] = f2bf(v);
      }
    }
  }
}

// ---------------- sliding-window attention ----------------
// grid (C=16, H=12, B=2), block 256: thread p owns query p of chunk c.
// Online softmax over 5 sub-tiles of 128 keys covering [pg-256, pg+256].
__global__ __launch_bounds__(256) void attn_sliding(
    const u16* __restrict__ qkv,     // [NTOK][2304]: q|k|v
    const int* __restrict__ mask,    // [NB][S_LEN]
    u16* __restrict__ attnO)         // [NTOK][768]
{
  __shared__ __attribute__((aligned(16))) u16 Ks[128*64];
  __shared__ __attribute__((aligned(16))) u16 Vs[128*64];
  __shared__ unsigned char Mk[128];
  const int c = blockIdx.x, hh = blockIdx.y, b = blockIdx.z;
  const int p = threadIdx.x;
  const int pg = c*WWIN + p;                 // global query position
  const size_t qrow = (size_t)b*S_LEN + pg;
  const u16* qp = qkv + qrow*2304 + hh*DHEAD;
  float q[64];
  #pragma unroll
  for (int dg=0; dg<64; dg+=8){
    uint4 u = *(const uint4*)(qp+dg);
    q[dg+0]=blo(u.x); q[dg+1]=bhi(u.x);
    q[dg+2]=blo(u.y); q[dg+3]=bhi(u.y);
    q[dg+4]=blo(u.z); q[dg+5]=bhi(u.z);
    q[dg+6]=blo(u.w); q[dg+7]=bhi(u.w);
  }
  float O[64];
  #pragma unroll
  for (int d=0;d<64;d++) O[d]=0.f;
  float m=-1e30f, l=0.f;

  for (int st=0; st<5; st++){                // 5 sub-tiles x 128 keys cover [pg-256, pg+256]
    const int base = (c-1)*WWIN + st*128;
    __syncthreads();   // previous sub-tile's LDS reads complete
    #pragma unroll
    for (int it=0; it<4; it++){
      int idx = it*256 + p;                  // 0..1023
      int j = idx>>3, dg = (idx&7)*8;
      int g = base + j;
      uint4 kv = {0,0,0,0}, vv = {0,0,0,0};
      if (g>=0 && g<S_LEN){
        const u16* kb = qkv + ((size_t)b*S_LEN+g)*2304 + 768 + hh*DHEAD + dg;
        kv = *(const uint4*)kb;
        vv = *(const uint4*)(kb + 768);
      }
      *(uint4*)&Ks[j*64+dg] = kv;
      *(uint4*)&Vs[j*64+dg] = vv;
    }
    if (p < 128){
      int g = base + p;
      Mk[p] = (g>=0 && g<S_LEN) ? (unsigned char)(mask[b*S_LEN+g]!=0) : (unsigned char)0;
    }
    __syncthreads();

    int lo = pg - WWIN - base; if (lo < 0) lo = 0;
    int hi = pg + WWIN - base; if (hi > 127) hi = 127;
    for (int j=lo; j<=hi; j++){
      if (!Mk[j]) continue;
      float s=0.f;
      #pragma unroll
      for (int dg=0;dg<64;dg+=8){
        uint4 u = *(const uint4*)&Ks[j*64+dg];
        s += blo(u.x)*q[dg+0]+bhi(u.x)*q[dg+1]+blo(u.y)*q[dg+2]+bhi(u.y)*q[dg+3]
           + blo(u.z)*q[dg+4]+bhi(u.z)*q[dg+5]+blo(u.w)*q[dg+6]+bhi(u.w)*q[dg+7];
      }
      s *= 0.125f;                       // 1/sqrt(64)
      if (s > m){
        float corr = __expf(m - s);
        m = s; l *= corr;
        #pragma unroll
        for (int d=0;d<64;d++) O[d]*=corr;
      }
      float w = __expf(s - m);
      l += w;
      #pragma unroll
      for (int dg=0;dg<64;dg+=8){
        uint4 u = *(const uint4*)&Vs[j*64+dg];
        O[dg+0]+=w*blo(u.x); O[dg+1]+=w*bhi(u.x);
        O[dg+2]+=w*blo(u.y); O[dg+3]+=w*bhi(u.y);
        O[dg+4]+=w*blo(u.z); O[dg+5]+=w*bhi(u.z);
        O[dg+6]+=w*blo(u.w); O[dg+7]+=w*bhi(u.w);
      }
    }
  }
  float inv = 1.0f/l;
  u16* op = attnO + qrow*DMODEL + hh*DHEAD;
  #pragma unroll
  for (int dg=0;dg<64;dg+=8){
    uint4 u;
    u.x = pk(O[dg+0]*inv, O[dg+1]*inv);
    u.y = pk(O[dg+2]*inv, O[dg+3]*inv);
    u.z = pk(O[dg+4]*inv, O[dg+5]*inv);
    u.w = pk(O[dg+6]*inv, O[dg+7]*inv);
    *(uint4*)(op+dg) = u;
  }
}

// ---------------- regression head ----------------
__global__ __launch_bounds__(256) void head_kernel(
    const float* __restrict__ hf, const void* __restrict__ Wr1,
    const void* __restrict__ br1, const void* __restrict__ Wr2,
    const void* __restrict__ br2, void* __restrict__ outp,
    const int* __restrict__ flag)
{
  const int isF32 = *flag;
  int b = blockIdx.x, t = threadIdx.x;
  __shared__ float xs[DMODEL];
  const float* x = hf + (size_t)b*S_LEN*DMODEL;   // pooled = row 0 of batch b
  for (int i=t;i<DMODEL;i+=256) xs[i]=x[i];
  __syncthreads();
  float acc=0.f;
  #pragma unroll
  for (int jj=0;jj<2;jj++){
    int jcol = t + jj*256;
    float hsum = ldf(br1, jcol, isF32);
    for (int d=0;d<DMODEL;d++) hsum += xs[d]*ldf(Wr1, (long)d*512 + jcol, isF32);
    hsum = fmaxf(hsum, 0.f);
    acc += hsum * ldf(Wr2, jcol, isF32);
  }
  #pragma unroll
  for (int off=32; off>=1; off>>=1) acc += __shfl_down(acc, off, 64);
  __shared__ float rs[4];
  if ((t&63)==0) rs[t>>6]=acc;
  __syncthreads();
  if (t==0){
    float val = rs[0]+rs[1]+rs[2]+rs[3] + ldf(br2, 0, isF32);
    if (isF32) ((float*)outp)[b] = val;
    else       ((u16*)outp)[b]   = f2bf(val);
  }
}

// ---------------- workspace layout (bytes), total 102,236,416 (~97.5 MiB) ----------------
// Liveness chaining: delta holds the bf16 copy of the current residual (emitted
// by embed_ln/add_ln) between LN and the next GEMM that consumes it; ffn1 spans
// OFF_X..OFF_DLT (qkv + attO regions, both dead during the FFN).
static const size_t OFF_WT   = 0;          // 14,155,776: qkvT|woT|wiT|wfT (one layer, reused)
static const size_t OFF_FLAG = 14155776;   // 256
static const size_t OFF_HF   = 14156032;   // 25,165,824 fp32 residual
static const size_t OFF_X    = 39321856;   // 37,748,736 qkv [8192][2304] bf16
static const size_t OFF_ATT  = 77070592;   // 12,582,912 attO bf16
static const size_t OFF_DLT  = 89653504;   // 12,582,912 delta/hb bf16
// ffn1 = [8192][3072] bf16 = 50,331,648 B = OFF_X .. OFF_DLT exactly.

extern "C" void kernel_launch(void* const* d_in, const int* in_sizes, int n_in,
                              void* d_out, int out_size, void* d_ws, size_t ws_size,
                              hipStream_t stream)
{
  const int*  ids   = (const int*)d_in[0];
  const int*  amask = (const int*)d_in[1];
  const void* wemb  = d_in[2];
  const void* pemb  = d_in[3];
  const void* temb  = d_in[4];
  const void* elnw  = d_in[5];
  const void* elnb  = d_in[6];
  const void* Wq    = d_in[7];
  const void* bq    = d_in[8];
  const void* Wk    = d_in[9];
  const void* bk    = d_in[10];
  const void* Wv    = d_in[11];
  const void* bv    = d_in[12];
  const void* Wo    = d_in[13];
  const void* bo    = d_in[14];
  const void* ln1w  = d_in[15];
  const void* ln1b  = d_in[16];
  const void* Wi    = d_in[17];
  const void* bi    = d_in[18];
  const void* Wf    = d_in[19];
  const void* bfb   = d_in[20];
  const void* ln2w  = d_in[21];
  const void* ln2b  = d_in[22];
  const void* Wr1   = d_in[23];
  const void* br1   = d_in[24];
  const void* Wr2   = d_in[25];
  const void* br2   = d_in[26];

  char* ws = (char*)d_ws;
  u16*   qkvT   = (u16*)  (ws + OFF_WT);                 // [2304][768]
  u16*   woT    = qkvT + (size_t)2304*768;               // [768][768]
  u16*   wiT    = woT  + (size_t)768*768;                // [3072][768]
  u16*   wfT    = wiT  + (size_t)3072*768;               // [768][3072]
  int*   flag   = (int*)  (ws + OFF_FLAG);
  float* hf     = (float*)(ws + OFF_HF);
  u16*   qkvbuf = (u16*)  (ws + OFF_X);
  u16*   ffn1   = (u16*)  (ws + OFF_X);                  // spans OFF_X..OFF_DLT
  u16*   attO   = (u16*)  (ws + OFF_ATT);
  u16*   delta  = (u16*)  (ws + OFF_DLT);                // doubles as bf16 residual copy

  const long wDD = (long)768*768, wDF = (long)768*3072;
  dim3 tb(32,8);

  probe_dtype<<<1, 1, 0, stream>>>((const u16*)elnw, flag);
  // emits fp32 hf + bf16 copy into delta
  embed_ln<<<NTOK, 256, 0, stream>>>(ids, wemb, pemb, temb, elnw, elnb, hf, delta, flag);

  for (int l=0; l<NLAYER; l++){
    transpose_off<<<dim3(24,24), tb, 0, stream>>>(Wq, (long)l*wDD, qkvT,            768, 768,  flag);
    transpose_off<<<dim3(24,24), tb, 0, stream>>>(Wk, (long)l*wDD, qkvT + 768*768,  768, 768,  flag);
    transpose_off<<<dim3(24,24), tb, 0, stream>>>(Wv, (long)l*wDD, qkvT + 1536*768, 768, 768,  flag);
    transpose_off<<<dim3(24,24), tb, 0, stream>>>(Wo, (long)l*wDD, woT,             768, 768,  flag);
    transpose_off<<<dim3(96,24), tb, 0, stream>>>(Wi, (long)l*wDF, wiT,             768, 3072, flag);
    transpose_off<<<dim3(24,96), tb, 0, stream>>>(Wf, (long)l*wDF, wfT,             3072, 768, flag);

    // QKV projection (packed N=2304), A = bf16 residual copy (delta)
    gemm128<false><<<dim3(18,64), 256, 0, stream>>>(
        delta, qkvT, bq, bk, bv, 768, (long)l*768, qkvbuf, NTOK, 2304, 768, flag);
    // sliding-window attention -> bf16 [NTOK,768]
    attn_sliding<<<dim3(NCHUNK,NHEAD,NB), 256, 0, stream>>>(qkvbuf, amask, attO);
    // output projection -> bf16 delta (overwrites the residual copy, already consumed)
    gemm128<false><<<dim3(6,64), 256, 0, stream>>>(
        attO, woT, bo, bo, bo, 768, (long)l*768, delta, NTOK, 768, 768, flag);
    // residual+LN; re-emits normalized bf16 into delta (in-place)
    add_ln<<<NTOK, 256, 0, stream>>>(hf, delta, ln1w, ln1b, (long)l*768, delta, flag);

    // FFN, un-chunked (ffn1 spans the dead qkv+attO regions)
    gemm128<true><<<dim3(24,64), 256, 0, stream>>>(
        delta, wiT, bi, bi, bi, 3072, (long)l*3072, ffn1, NTOK, 3072, 768, flag);
    gemm128<false><<<dim3(6,64), 256, 0, stream>>>(
        ffn1, wfT, bfb, bfb, bfb, 768, (long)l*768, delta, NTOK, 768, 3072, flag);
    add_ln<<<NTOK, 256, 0, stream>>>(hf, delta, ln2w, ln2b, (long)l*768, delta, flag);
  }

  head_kernel<<<NB, 256, 0, stream>>>(hf, Wr1, br1, Wr2, br2, d_out, flag);
}

// Round 4
// 5604.088 us; speedup vs baseline: 2.3288x; 2.0070x over previous
//
#include <hip/hip_runtime.h>
#include <stdint.h>

// ---------------- model constants ----------------
#define S_LEN 4096
#define NB 2
#define DMODEL 768
#define NHEAD 12
#define DHEAD 64
#define WWIN 256
#define FDIM 3072
#define NLAYER 12
#define NTOK 8192      // NB * S_LEN

typedef unsigned short u16;
typedef __attribute__((ext_vector_type(8))) short bf16x8;
typedef __attribute__((ext_vector_type(4))) float f32x4;

__device__ __forceinline__ float bf2f(u16 u){ return __builtin_bit_cast(float, (uint32_t)(((uint32_t)u)<<16)); }
__device__ __forceinline__ u16 f2bf(float f){
  uint32_t x = __builtin_bit_cast(uint32_t, f);
  x += 0x7fffu + ((x>>16)&1u);     // RNE
  return (u16)(x>>16);
}
__device__ __forceinline__ uint32_t pk(float a, float b){
  return (uint32_t)f2bf(a) | ((uint32_t)f2bf(b)<<16);
}
// flag-aware load of an input float array (isF32: 1 = fp32, 0 = bf16)
__device__ __forceinline__ float ldf(const void* p, long i, int isF32){
  return isF32 ? ((const float*)p)[i] : bf2f(((const u16*)p)[i]);
}
// async global->LDS, 16B per lane; lds must be wave-uniform (HW: base + lane*16)
__device__ __forceinline__ void async_ld16(u16* lds, const u16* g){
  __builtin_amdgcn_global_load_lds(
      (const __attribute__((address_space(1))) unsigned int*)g,
      (__attribute__((address_space(3))) unsigned int*)lds,
      16, 0, 0);
}

// ---------------- dtype probe: emb_ln_w is ones ----------------
__global__ void probe_dtype(const u16* __restrict__ lnw, int* __restrict__ flag){
  if (threadIdx.x==0 && blockIdx.x==0) *flag = (lnw[0]==0x3F80) ? 0 : 1;
}

// ---------------- block reduce (sum, sumsq) ----------------
__device__ __forceinline__ void block_reduce2(float& s, float& ss, int t){
  #pragma unroll
  for (int off=32; off>=1; off>>=1){
    s  += __shfl_down(s,  off, 64);
    ss += __shfl_down(ss, off, 64);
  }
  __shared__ float rs[4], rss[4];
  if ((t&63)==0){ rs[t>>6]=s; rss[t>>6]=ss; }
  __syncthreads();
  s  = rs[0]+rs[1]+rs[2]+rs[3];
  ss = rss[0]+rss[1]+rss[2]+rss[3];
}

// ---------------- weight transpose with element offset (any float dtype -> bf16) ----------------
__global__ __launch_bounds__(256) void transpose_off(
    const void* __restrict__ in, long eoff, u16* __restrict__ out,
    int R, int C, const int* __restrict__ flag)
{
  const int isF32 = *flag;
  __shared__ u16 tile[32][33];
  int x = blockIdx.x*32 + threadIdx.x;
  int ybase = blockIdx.y*32;
  #pragma unroll
  for (int j=threadIdx.y; j<32; j+=8){
    long idx = eoff + (long)(ybase+j)*C + x;
    tile[j][threadIdx.x] = isF32 ? f2bf(((const float*)in)[idx])
                                 : ((const u16*)in)[idx];
  }
  __syncthreads();
  int ox = ybase + threadIdx.x;
  int oybase = blockIdx.x*32;
  #pragma unroll
  for (int j=threadIdx.y; j<32; j+=8)
    out[(size_t)(oybase+j)*R + ox] = tile[threadIdx.x][j];
}

// ---------------- embedding gather + LayerNorm (writes fp32 hf AND bf16 hb) ----------------
__global__ __launch_bounds__(256) void embed_ln(
    const int* __restrict__ ids, const void* __restrict__ wemb,
    const void* __restrict__ pemb, const void* __restrict__ temb,
    const void* __restrict__ gw, const void* __restrict__ gb,
    float* __restrict__ hf, u16* hb, const int* __restrict__ flag)
{
  const int isF32 = *flag;
  int r = blockIdx.x, t = threadIdx.x;
  int spos = r & (S_LEN-1);
  int tok = ids[r];
  size_t base = (size_t)r*DMODEL;
  float x[3]; float s=0.f, ss=0.f;
  #pragma unroll
  for (int i=0;i<3;i++){
    int idx = t + 256*i;
    float v = ldf(wemb, (long)tok*DMODEL+idx, isF32)
            + ldf(pemb, (long)(spos+2)*DMODEL+idx, isF32)
            + ldf(temb, idx, isF32);
    x[i]=v; s+=v; ss+=v*v;
  }
  block_reduce2(s, ss, t);
  float mu = s*(1.f/768.f);
  float var = ss*(1.f/768.f) - mu*mu;
  float rstd = rsqrtf(var + 1e-5f);
  #pragma unroll
  for (int i=0;i<3;i++){
    int idx = t + 256*i;
    float y = (x[i]-mu)*rstd*ldf(gw,idx,isF32) + ldf(gb,idx,isF32);
    hf[base+idx] = y;
    hb[base+idx] = f2bf(y);
  }
}

// ---------------- residual add + LayerNorm; hb may alias delta (thread-local RAW only) ----------------
__global__ __launch_bounds__(256) void add_ln(
    float* __restrict__ hf, const u16* delta,
    const void* __restrict__ gw, const void* __restrict__ gb, long goff,
    u16* hb, const int* __restrict__ flag)
{
  const int isF32 = *flag;
  int r = blockIdx.x, t = threadIdx.x;
  size_t base = (size_t)r*DMODEL;
  float x[3]; float s=0.f, ss=0.f;
  #pragma unroll
  for (int i=0;i<3;i++){
    int idx = t + 256*i;
    float v = hf[base+idx] + bf2f(delta[base+idx]);
    x[i]=v; s+=v; ss+=v*v;
  }
  block_reduce2(s, ss, t);
  float mu = s*(1.f/768.f);
  float var = ss*(1.f/768.f) - mu*mu;
  float rstd = rsqrtf(var + 1e-5f);
  #pragma unroll
  for (int i=0;i<3;i++){
    int idx = t + 256*i;
    float y = (x[i]-mu)*rstd*ldf(gw,goff+idx,isF32) + ldf(gb,goff+idx,isF32);
    hf[base+idx] = y;
    hb[base+idx] = f2bf(y);
  }
}

// ---------------- bf16 MFMA GEMM, m97 structure ----------------
// C[M,N] = A[M,K] * Bt[N,K]^T + bias -> bf16.
// 128x128 tile, BK=64, 4 waves each computing 64x64 (4x4 of 16x16x32 MFMA).
// VSPLIT (QKV projection only): logical N=2304; cols <1536 (q|k) go to Cb with
// row stride 1536; cols >=1536 (v) are scattered TRANSPOSED into
// vT[col-1536][row] at Cb + NTOK*1536 — attention then stages V^T rows directly.
template<bool GELU, bool VSPLIT>
__global__ __launch_bounds__(256) void gemm128(
    const u16* __restrict__ A, const u16* __restrict__ Bt,
    const void* __restrict__ b0, const void* __restrict__ b1,
    const void* __restrict__ b2, int bw, long boff,
    u16* __restrict__ Cb, int M, int N, int K, const int* __restrict__ flag)
{
  const int isF32 = *flag;
  __shared__ __attribute__((aligned(16))) u16 As[128*64];
  __shared__ __attribute__((aligned(16))) u16 Bs[128*64];
  const int t = threadIdx.x;
  const int lane = t & 63, wave = t >> 6;
  const int mBase = blockIdx.y*128, nBase = blockIdx.x*128;
  const int wm = (wave>>1)*64, wn = (wave&1)*64;
  const int lrow = lane & 15, quad = lane >> 4;
  f32x4 acc[4][4] = {};

  const int sr = wave*8 + (lane>>3);
  const int sc = (lane&7)*8;
  const u16* Ag = A  + (size_t)(mBase + sr)*K + sc;
  const u16* Bg = Bt + (size_t)(nBase + sr)*K + sc;
  u16* AsW = &As[(wave*8)*64];
  u16* BsW = &Bs[(wave*8)*64];

  for (int k0 = 0; k0 < K; k0 += 64){
    __syncthreads();
    #pragma unroll
    for (int i=0;i<4;i++){
      async_ld16(AsW + i*32*64, Ag + (size_t)i*32*K + k0);
      async_ld16(BsW + i*32*64, Bg + (size_t)i*32*K + k0);
    }
    __syncthreads();
    #pragma unroll
    for (int kk=0; kk<64; kk+=32){
      bf16x8 af[4], bg[4];
      #pragma unroll
      for (int mi=0;mi<4;mi++) af[mi] = *(const bf16x8*)&As[(wm+mi*16+lrow)*64 + kk + quad*8];
      #pragma unroll
      for (int ni=0;ni<4;ni++) bg[ni] = *(const bf16x8*)&Bs[(wn+ni*16+lrow)*64 + kk + quad*8];
      #pragma unroll
      for (int mi=0;mi<4;mi++){
        #pragma unroll
        for (int ni=0;ni<4;ni++){
          acc[mi][ni] = __builtin_amdgcn_mfma_f32_16x16x32_bf16(af[mi], bg[ni], acc[mi][ni], 0,0,0);
        }
      }
    }
  }

  u16* vT = Cb + (size_t)NTOK*1536;   // only used when VSPLIT
  #pragma unroll
  for (int mi=0;mi<4;mi++){
    #pragma unroll
    for (int ni=0;ni<4;ni++){
      int col = nBase + wn + ni*16 + lrow;
      const void* bp; long bidx;
      if      (col <   bw){ bp=b0; bidx=boff+col; }
      else if (col < 2*bw){ bp=b1; bidx=boff+col-bw; }
      else                { bp=b2; bidx=boff+col-2*bw; }
      float bval = ldf(bp, bidx, isF32);
      #pragma unroll
      for (int r=0;r<4;r++){
        int row = mBase + wm + mi*16 + quad*4 + r;
        float v = acc[mi][ni][r] + bval;
        if (GELU) v = 0.5f*v*(1.0f + erff(v*0.70710678118654752f));
        if (VSPLIT){
          if (col < 1536) Cb[(size_t)row*1536 + col] = f2bf(v);
          else            vT[(size_t)(col-1536)*NTOK + row] = f2bf(v);
        } else {
          Cb[(size_t)row*N + col] = f2bf(v);
        }
      }
    }
  }
}

// ---------------- MFMA flash attention ----------------
// grid (32, 12, 2): block owns 128 queries (qb..qb+127) of head hh, batch b.
// 4 waves x 32 queries each. 10 subtiles of 64 keys cover [qb-256, qb+384).
// Online softmax per query row; P transposed through per-wave LDS buffer.
// qk: [NTOK][1536] bf16 (q|k packed); vT: [768][NTOK] bf16 (V transposed).
__global__ __launch_bounds__(256) void attn_mfma(
    const u16* __restrict__ qk, const u16* __restrict__ vT,
    const int* __restrict__ mask, u16* __restrict__ attnO)
{
  __shared__ __attribute__((aligned(16))) u16 Ks[64*64];    // [key][dh]
  __shared__ __attribute__((aligned(16))) u16 Vt[64*72];    // [dh][key+pad]
  __shared__ __attribute__((aligned(16))) u16 Ps[4][32*72]; // per-wave [q][key+pad]
  __shared__ unsigned char Mk[64];
  const int t = threadIdx.x;
  const int lane = t & 63, wave = t >> 6;
  const int lrow = lane & 15, quad = lane >> 4;
  const int qb = blockIdx.x*128, hh = blockIdx.y, b = blockIdx.z;
  const int b4 = b*S_LEN;
  const int woff = wave*32;

  // Q fragments (A-operand): lane reads Q row (qb+woff+mi*16+lrow), k-chunk quad*8
  bf16x8 qf[2][2];
  #pragma unroll
  for (int mi=0;mi<2;mi++)
    #pragma unroll
    for (int kk=0;kk<2;kk++)
      qf[mi][kk] = *(const bf16x8*)&qk[(size_t)(b4 + qb + woff + mi*16 + lrow)*1536
                                       + hh*64 + kk*32 + quad*8];

  f32x4 oacc[2][4] = {};
  float m[2][4], l[2][4];
  #pragma unroll
  for (int mi=0;mi<2;mi++)
    #pragma unroll
    for (int r=0;r<4;r++){ m[mi][r] = -1e30f; l[mi][r] = 0.f; }

  for (int st=0; st<10; st++){
    const int bk = qb - 256 + st*64;
    __syncthreads();
    // stage K [64][64]
    #pragma unroll
    for (int i=0;i<2;i++){
      int idx2 = t + 256*i;
      int j = idx2>>3, dg = (idx2&7)*8;
      int g = bk + j;
      uint4 kv = {0,0,0,0};
      if (g>=0 && g<S_LEN)
        kv = *(const uint4*)&qk[(size_t)(b4+g)*1536 + 768 + hh*64 + dg];
      *(uint4*)&Ks[j*64+dg] = kv;
    }
    // stage V^T [64][72] from vT global (rows=dh, contiguous in token)
    #pragma unroll
    for (int i=0;i<2;i++){
      int idx2 = t + 256*i;
      int dh = idx2>>3, kb = (idx2&7)*8;
      int g0 = bk + kb;                       // multiple of 8; all 8 same side
      uint4 vv = {0,0,0,0};
      if (g0>=0 && g0<S_LEN)
        vv = *(const uint4*)&vT[(size_t)(hh*64+dh)*NTOK + b4 + g0];
      *(uint4*)&Vt[dh*72+kb] = vv;
    }
    if (t < 64){
      int g = bk + t;
      Mk[t] = (g>=0 && g<S_LEN) ? (unsigned char)(mask[b4+g]!=0) : (unsigned char)0;
    }
    __syncthreads();

    // QK^T: S[32q][64k] per wave
    f32x4 sacc[2][4] = {};
    #pragma unroll
    for (int kk=0;kk<2;kk++){
      bf16x8 kf[4];
      #pragma unroll
      for (int ni=0;ni<4;ni++)
        kf[ni] = *(const bf16x8*)&Ks[(ni*16+lrow)*64 + kk*32 + quad*8];
      #pragma unroll
      for (int mi=0;mi<2;mi++)
        #pragma unroll
        for (int ni=0;ni<4;ni++)
          sacc[mi][ni] = __builtin_amdgcn_mfma_f32_16x16x32_bf16(qf[mi][kk], kf[ni], sacc[mi][ni], 0,0,0);
    }

    // mask + online softmax (row = quad*4+r within 16-group; col = ni*16+lrow)
    #pragma unroll
    for (int mi=0;mi<2;mi++){
      float rowm[4] = {-INFINITY,-INFINITY,-INFINITY,-INFINITY};
      #pragma unroll
      for (int ni=0;ni<4;ni++){
        int kloc = ni*16 + lrow;
        int dbase = bk + kloc - (qb + woff + mi*16 + quad*4);
        bool mk = Mk[kloc] != 0;
        #pragma unroll
        for (int r=0;r<4;r++){
          int d = dbase - r;
          bool valid = mk && (d >= -(int)WWIN) && (d <= (int)WWIN);
          float sv = valid ? sacc[mi][ni][r]*0.125f : -INFINITY;
          sacc[mi][ni][r] = sv;
          rowm[r] = fmaxf(rowm[r], sv);
        }
      }
      #pragma unroll
      for (int r=0;r<4;r++){
        #pragma unroll
        for (int off=1; off<16; off<<=1)
          rowm[r] = fmaxf(rowm[r], __shfl_xor(rowm[r], off, 64));
        float newm = fmaxf(m[mi][r], rowm[r]);      // stays >= -1e30 (NaN-safe)
        float f = __expf(m[mi][r] - newm);
        m[mi][r] = newm;
        float rs = 0.f;
        #pragma unroll
        for (int ni=0;ni<4;ni++){
          float p = __expf(sacc[mi][ni][r] - newm); // -inf -> 0
          sacc[mi][ni][r] = p;
          rs += p;
          oacc[mi][ni][r] *= f;
        }
        #pragma unroll
        for (int off=1; off<16; off<<=1)
          rs += __shfl_xor(rs, off, 64);
        l[mi][r] = l[mi][r]*f + rs;
        // write P^T-ready layout: Ps[q_local][key]
        #pragma unroll
        for (int ni=0;ni<4;ni++)
          Ps[wave][(mi*16 + quad*4 + r)*72 + ni*16 + lrow] = f2bf(sacc[mi][ni][r]);
      }
    }

    // PV: O[32q][64dh] += P[32q][64k] * V^T[64dh][64k]^T
    #pragma unroll
    for (int kk=0;kk<2;kk++){
      bf16x8 pf[2], vf[4];
      #pragma unroll
      for (int mi=0;mi<2;mi++)
        pf[mi] = *(const bf16x8*)&Ps[wave][(mi*16+lrow)*72 + kk*32 + quad*8];
      #pragma unroll
      for (int ni=0;ni<4;ni++)
        vf[ni] = *(const bf16x8*)&Vt[(ni*16+lrow)*72 + kk*32 + quad*8];
      #pragma unroll
      for (int mi=0;mi<2;mi++)
        #pragma unroll
        for (int ni=0;ni<4;ni++)
          oacc[mi][ni] = __builtin_amdgcn_mfma_f32_16x16x32_bf16(pf[mi], vf[ni], oacc[mi][ni], 0,0,0);
    }
  }

  // epilogue: normalize and store
  #pragma unroll
  for (int mi=0;mi<2;mi++){
    #pragma unroll
    for (int r=0;r<4;r++){
      float inv = 1.0f / l[mi][r];
      size_t row = (size_t)(b4 + qb + woff + mi*16 + quad*4 + r);
      #pragma unroll
      for (int ni=0;ni<4;ni++)
        attnO[row*DMODEL + hh*64 + ni*16 + lrow] = f2bf(oacc[mi][ni][r]*inv);
    }
  }
}

// ---------------- regression head ----------------
__global__ __launch_bounds__(256) void head_kernel(
    const float* __restrict__ hf, const void* __restrict__ Wr1,
    const void* __restrict__ br1, const void* __restrict__ Wr2,
    const void* __restrict__ br2, void* __restrict__ outp,
    const int* __restrict__ flag)
{
  const int isF32 = *flag;
  int b = blockIdx.x, t = threadIdx.x;
  __shared__ float xs[DMODEL];
  const float* x = hf + (size_t)b*S_LEN*DMODEL;
  for (int i=t;i<DMODEL;i+=256) xs[i]=x[i];
  __syncthreads();
  float acc=0.f;
  #pragma unroll
  for (int jj=0;jj<2;jj++){
    int jcol = t + jj*256;
    float hsum = ldf(br1, jcol, isF32);
    for (int d=0;d<DMODEL;d++) hsum += xs[d]*ldf(Wr1, (long)d*512 + jcol, isF32);
    hsum = fmaxf(hsum, 0.f);
    acc += hsum * ldf(Wr2, jcol, isF32);
  }
  #pragma unroll
  for (int off=32; off>=1; off>>=1) acc += __shfl_down(acc, off, 64);
  __shared__ float rs[4];
  if ((t&63)==0) rs[t>>6]=acc;
  __syncthreads();
  if (t==0){
    float val = rs[0]+rs[1]+rs[2]+rs[3] + ldf(br2, 0, isF32);
    if (isF32) ((float*)outp)[b] = val;
    else       ((u16*)outp)[b]   = f2bf(val);
  }
}

// ---------------- workspace layout (bytes), total 102,236,416 (~97.5 MiB) ----------------
// OFF_X region now holds qk [8192][1536] (25.2MB) followed by vT [768][8192]
// (12.6MB) = 37.75MB exactly. ffn1 spans OFF_X..OFF_DLT (qk+vT+attO all dead then).
static const size_t OFF_WT   = 0;          // 14,155,776: qkvT|woT|wiT|wfT
static const size_t OFF_FLAG = 14155776;   // 256
static const size_t OFF_HF   = 14156032;   // 25,165,824 fp32 residual
static const size_t OFF_X    = 39321856;   // 37,748,736 qk | vT
static const size_t OFF_ATT  = 77070592;   // 12,582,912 attO bf16
static const size_t OFF_DLT  = 89653504;   // 12,582,912 delta/hb bf16

extern "C" void kernel_launch(void* const* d_in, const int* in_sizes, int n_in,
                              void* d_out, int out_size, void* d_ws, size_t ws_size,
                              hipStream_t stream)
{
  const int*  ids   = (const int*)d_in[0];
  const int*  amask = (const int*)d_in[1];
  const void* wemb  = d_in[2];
  const void* pemb  = d_in[3];
  const void* temb  = d_in[4];
  const void* elnw  = d_in[5];
  const void* elnb  = d_in[6];
  const void* Wq    = d_in[7];
  const void* bq    = d_in[8];
  const void* Wk    = d_in[9];
  const void* bk    = d_in[10];
  const void* Wv    = d_in[11];
  const void* bv    = d_in[12];
  const void* Wo    = d_in[13];
  const void* bo    = d_in[14];
  const void* ln1w  = d_in[15];
  const void* ln1b  = d_in[16];
  const void* Wi    = d_in[17];
  const void* bi    = d_in[18];
  const void* Wf    = d_in[19];
  const void* bfb   = d_in[20];
  const void* ln2w  = d_in[21];
  const void* ln2b  = d_in[22];
  const void* Wr1   = d_in[23];
  const void* br1   = d_in[24];
  const void* Wr2   = d_in[25];
  const void* br2   = d_in[26];

  char* ws = (char*)d_ws;
  u16*   qkvT   = (u16*)  (ws + OFF_WT);                 // [2304][768]
  u16*   woT    = qkvT + (size_t)2304*768;               // [768][768]
  u16*   wiT    = woT  + (size_t)768*768;                // [3072][768]
  u16*   wfT    = wiT  + (size_t)3072*768;               // [768][3072]
  int*   flag   = (int*)  (ws + OFF_FLAG);
  float* hf     = (float*)(ws + OFF_HF);
  u16*   qkbuf  = (u16*)  (ws + OFF_X);                  // [8192][1536]
  u16*   vTbuf  = qkbuf + (size_t)NTOK*1536;             // [768][8192]
  u16*   ffn1   = (u16*)  (ws + OFF_X);                  // spans OFF_X..OFF_DLT
  u16*   attO   = (u16*)  (ws + OFF_ATT);
  u16*   delta  = (u16*)  (ws + OFF_DLT);                // bf16 residual copy

  const long wDD = (long)768*768, wDF = (long)768*3072;
  dim3 tb(32,8);

  probe_dtype<<<1, 1, 0, stream>>>((const u16*)elnw, flag);
  embed_ln<<<NTOK, 256, 0, stream>>>(ids, wemb, pemb, temb, elnw, elnb, hf, delta, flag);

  for (int l=0; l<NLAYER; l++){
    transpose_off<<<dim3(24,24), tb, 0, stream>>>(Wq, (long)l*wDD, qkvT,            768, 768,  flag);
    transpose_off<<<dim3(24,24), tb, 0, stream>>>(Wk, (long)l*wDD, qkvT + 768*768,  768, 768,  flag);
    transpose_off<<<dim3(24,24), tb, 0, stream>>>(Wv, (long)l*wDD, qkvT + 1536*768, 768, 768,  flag);
    transpose_off<<<dim3(24,24), tb, 0, stream>>>(Wo, (long)l*wDD, woT,             768, 768,  flag);
    transpose_off<<<dim3(96,24), tb, 0, stream>>>(Wi, (long)l*wDF, wiT,             768, 3072, flag);
    transpose_off<<<dim3(24,96), tb, 0, stream>>>(Wf, (long)l*wDF, wfT,             3072, 768, flag);

    // QKV projection (logical N=2304): q|k -> qkbuf [8192][1536], v -> vTbuf transposed
    gemm128<false,true><<<dim3(18,64), 256, 0, stream>>>(
        delta, qkvT, bq, bk, bv, 768, (long)l*768, qkbuf, NTOK, 2304, 768, flag);
    // MFMA flash attention -> bf16 [NTOK,768]
    attn_mfma<<<dim3(32,NHEAD,NB), 256, 0, stream>>>(qkbuf, vTbuf, amask, attO);
    // output projection -> bf16 delta
    gemm128<false,false><<<dim3(6,64), 256, 0, stream>>>(
        attO, woT, bo, bo, bo, 768, (long)l*768, delta, NTOK, 768, 768, flag);
    add_ln<<<NTOK, 256, 0, stream>>>(hf, delta, ln1w, ln1b, (long)l*768, delta, flag);

    // FFN, un-chunked (ffn1 spans the dead qk+vT+attO regions)
    gemm128<true,false><<<dim3(24,64), 256, 0, stream>>>(
        delta, wiT, bi, bi, bi, 3072, (long)l*3072, ffn1, NTOK, 3072, 768, flag);
    gemm128<false,false><<<dim3(6,64), 256, 0, stream>>>(
        ffn1, wfT, bfb, bfb, bfb, 768, (long)l*768, delta, NTOK, 768, 3072, flag);
    add_ln<<<NTOK, 256, 0, stream>>>(hf, delta, ln2w, ln2b, (long)l*768, delta, flag);
  }

  head_kernel<<<NB, 256, 0, stream>>>(hf, Wr1, br1, Wr2, br2, d_out, flag);
}